// Round 1
// baseline (435.216 us; speedup 1.0000x reference)
//
#include <hip/hip_runtime.h>
#include <hip/hip_bf16.h>

// W8Linear: out[32,16384] = (x[32,4096] . W[16384,4096]^T) * scale[n] + bias[n]
// Harness dtypes: x/scale/bias fp32, weight int32 (268 MB), out fp32.
//
// Perf forensics:
//   R6: GEMM cold 123 us (2.2 TB/s HBM-sourced); request path 5.9 TB/s warm;
//       pipes idle (VALUBusy 6%, MfmaUtil 2.6%) -> DRAM-side read limit.
//   R8: 4 KB contiguous runs at 16 KB stride via global_load_lds -> NO change
//       (369.6 us). Run-length theory falsified for 0.5-4 KB.
//   R0 (this): harness fills hit 6.7 TB/s (linear writes) in the same bench.
//       Surviving theories for the 3x read gap: (A) global_load_lds DMA path
//       cap, (C) L3 allocate/evict churn vs the 1 GiB dirty poison, (D) the
//       16 KB row stride itself. This kernel removes all three:
//       block = 4 channels x full K = 64 KB PERFECTLY LINEAR region, read with
//       plain nontemporal per-lane dwordx4 (no DMA path, no L3 allocation),
//       reg -> ds_write staged. W has zero reuse so LDS is layout-only.
//       MFMA B rows 4..15 zeroed (waste irrelevant at 2.6% MfmaUtil).
//       2 blocks/CU keeps 2 streams live across the ~1 us compute phase.

typedef __attribute__((ext_vector_type(4))) int    i32x4;
typedef __attribute__((ext_vector_type(4))) float  f32x4;
typedef __attribute__((ext_vector_type(8))) short  s16x8;
typedef __attribute__((ext_vector_type(8))) __bf16 bf16x8;

constexpr int K = 4096;
constexpr int N = 16384;
constexpr int RPITCH = 16384 + 16;     // LDS bytes per weight row (16B pad)
constexpr size_t XB_OFF = 0;           // bf16 x: 32*4096*2 = 256 KB in d_ws

// fp32 -> bf16 RNE (finite inputs).
__device__ inline unsigned short f2bf_rne(float f) {
    unsigned u = __builtin_bit_cast(unsigned, f);
    u += 0x7FFF + ((u >> 16) & 1);
    return (unsigned short)(u >> 16);
}

// 8 int32 weights -> 8 bf16, exact (|w|<=127; fp32->bf16 truncation lossless).
__device__ inline bf16x8 cvtW(i32x4 lo, i32x4 hi) {
    s16x8 r;
#pragma unroll
    for (int i = 0; i < 4; ++i) {
        r[i]     = (short)(__builtin_bit_cast(unsigned, (float)lo[i]) >> 16);
        r[i + 4] = (short)(__builtin_bit_cast(unsigned, (float)hi[i]) >> 16);
    }
    return __builtin_bit_cast(bf16x8, r);
}

// ---- k1: x fp32 -> bf16 ----------------------------------------------------
__global__ __launch_bounds__(256) void xcvt_kernel(const float* __restrict__ x,
                                                   unsigned short* __restrict__ xb) {
    const int i = (blockIdx.x * 256 + threadIdx.x) * 8;
    f32x4 lo = *reinterpret_cast<const f32x4*>(x + i);
    f32x4 hi = *reinterpret_cast<const f32x4*>(x + i + 4);
    s16x8 r;
#pragma unroll
    for (int j = 0; j < 4; ++j) {
        r[j]     = (short)f2bf_rne(lo[j]);
        r[j + 4] = (short)f2bf_rne(hi[j]);
    }
    *reinterpret_cast<s16x8*>(xb + i) = r;
}

// ---- k2: GEMM, linear-stream nontemporal reg-staged ------------------------
__global__ __launch_bounds__(256, 2) void w8gemm_kernel(
    const __bf16* __restrict__ xb,
    const int* __restrict__ w,
    const float* __restrict__ scale,
    const float* __restrict__ bias,
    float* __restrict__ out)
{
    extern __shared__ char smem[];   // 4 * RPITCH = 65600 B

    const int tid  = threadIdx.x;
    const int lane = tid & 63;
    const int wave = tid >> 6;
    const int n16  = lane & 15;
    const int quad = lane >> 4;

    const int c0 = blockIdx.x * 4;        // 4 channels per block

    // ---- stage: one 64 KB linear region, nt loads -> regs -> LDS ----------
    // Round r: 256 threads cover bytes [r*4096, (r+1)*4096) of the region;
    // 16 rounds ascend linearly through 64 KB. All 16 loads in flight before
    // the writes drain them (progressive vmcnt).
    const char* gb = (const char*)(w + (size_t)c0 * K);
    i32x4 stg[16];
#pragma unroll
    for (int r = 0; r < 16; ++r)
        stg[r] = __builtin_nontemporal_load(
            reinterpret_cast<const i32x4*>(gb + r * 4096 + tid * 16));
#pragma unroll
    for (int r = 0; r < 16; ++r)
        *reinterpret_cast<i32x4*>(smem + (r >> 2) * RPITCH + (r & 3) * 4096
                                  + tid * 16) = stg[r];
    __syncthreads();

    // ---- compute: wave w consumes k-ints [w*1024, w*1024+1024) ------------
    // B fragment (16x16x32): channel n16 (<4 real, else zero), ints quad*8..+7.
    const char* lrow = smem + n16 * RPITCH + wave * 4096 + quad * 32;
    const __bf16* __restrict__ xr0 = xb + (size_t)n16 * K + wave * 1024 + quad * 8;
    const __bf16* __restrict__ xr1 = xr0 + (size_t)16 * K;

    f32x4 acc0 = {0.f, 0.f, 0.f, 0.f};
    f32x4 acc1 = {0.f, 0.f, 0.f, 0.f};
    const bool act = (n16 < 4);

#pragma unroll 1
    for (int jt = 0; jt < 4; ++jt) {
        // Prefetch this chunk's x fragments (8 k-steps x 2 token-halves).
        bf16x8 aX0[8], aX1[8];
#pragma unroll
        for (int j = 0; j < 8; ++j) {
            const int off = jt * 256 + j * 32;
            aX0[j] = *reinterpret_cast<const bf16x8*>(xr0 + off);
            aX1[j] = *reinterpret_cast<const bf16x8*>(xr1 + off);
        }
#pragma unroll
        for (int j = 0; j < 8; ++j) {
            i32x4 b0 = {0, 0, 0, 0};
            i32x4 b1 = {0, 0, 0, 0};
            if (act) {
                b0 = *reinterpret_cast<const i32x4*>(lrow + (jt * 8 + j) * 128);
                b1 = *reinterpret_cast<const i32x4*>(lrow + (jt * 8 + j) * 128 + 16);
            }
            bf16x8 bf = cvtW(b0, b1);
            acc0 = __builtin_amdgcn_mfma_f32_16x16x32_bf16(aX0[j], bf, acc0, 0, 0, 0);
            acc1 = __builtin_amdgcn_mfma_f32_16x16x32_bf16(aX1[j], bf, acc1, 0, 0, 0);
        }
    }

    // ---- cross-wave reduction (4 k-quarter partials) + scale/bias ---------
    __syncthreads();
    float* red = (float*)smem;           // 4 waves x 512 floats = 8 KB
#pragma unroll
    for (int v = 0; v < 4; ++v) {
        red[wave * 512 + lane * 8 + v]     = acc0[v];
        red[wave * 512 + lane * 8 + 4 + v] = acc1[v];
    }
    __syncthreads();
    if (tid < 128) {
        const int ch    = tid & 3;
        const int token = tid >> 2;                  // 0..31
        const int half  = token >> 4;                // acc0 vs acc1
        const int q     = (token >> 2) & 3;          // source quad
        const int v     = token & 3;                 // source reg
        const int slot  = (q * 16 + ch) * 8 + half * 4 + v;
        float s = red[slot] + red[512 + slot] + red[1024 + slot] + red[1536 + slot];
        const int c = c0 + ch;
        out[(size_t)token * N + c] = s * scale[c] + bias[c];
    }
}

extern "C" void kernel_launch(void* const* d_in, const int* in_sizes, int n_in,
                              void* d_out, int out_size, void* d_ws, size_t ws_size,
                              hipStream_t stream) {
    const float* x     = (const float*)d_in[0];
    const int*   w     = (const int*)d_in[1];
    const float* scale = (const float*)d_in[2];
    const float* bias  = (const float*)d_in[3];
    float* out = (float*)d_out;

    unsigned short* xb = (unsigned short*)((char*)d_ws + XB_OFF);

    xcvt_kernel<<<dim3(64), dim3(256), 0, stream>>>(x, xb);
    w8gemm_kernel<<<dim3(N / 4), dim3(256), 4 * RPITCH, stream>>>(
        (const __bf16*)xb, w, scale, bias, out);
}

// Round 2
// 367.975 us; speedup vs baseline: 1.1827x; 1.1827x over previous
//
#include <hip/hip_runtime.h>
#include <hip/hip_bf16.h>

// W8Linear: out[32,16384] = (x[32,4096] . W[16384,4096]^T) * scale[n] + bias[n]
// Harness dtype reality: x/scale/bias fp32 buffers (fp16 promoted); weight
// int32 (268 MB); out FLOAT32. Correct since R3 (absmax 2.0).
//
// Perf forensics:
//   R6 (4x-K calibration): GEMM cold = 123 us (2.2 TB/s); warm passes show
//     request path sustains 5.9 TB/s while HBM-sourced stays ~2.0 TB/s.
//     VALUBusy 6%, MfmaUtil 2.6% -> pipes idle, DRAM-side limit.
//   R7 (k-phase de-lockstep): no change -> temporal phase irrelevant.
//   R8 (4 KB contiguous runs, 369.6 us): run-length theory falsified.
//   R0' (4-ch linear 64 KB region, per-lane nt loads, reg-staged): 435 us.
//     REGRESSION -- confounded (structure + nt changed together). Full-region
//     temporal linearity is now also falsified as the lever.
//   Surviving theory: the 1 GiB harness poison-fill precedes the GEMM and
//     leaves L3 (256 MB, memory-side) full of DIRTY workspace lines. Our
//     268 MB weight read-allocate evicts ~256 MB of dirty lines -> mandatory
//     writebacks interleaved with reads -> mixed-RW DRAM rate ~2.1 TB/s.
//     Pure-write fill in the same bench: 6.7 TB/s.
//
// R1: single-variable test. EXACT R8 structure (best known, 369.6 us), only
// change: global_load_lds aux = 2 (gfx940+ NT bit) so weight reads are
// non-temporal (streaming, no-allocate) -> no dirty-line eviction storm.

typedef __attribute__((ext_vector_type(4))) int    i32x4;
typedef __attribute__((ext_vector_type(4))) float  f32x4;
typedef __attribute__((ext_vector_type(8))) short  s16x8;
typedef __attribute__((ext_vector_type(8))) __bf16 bf16x8;

constexpr int K = 4096;
constexpr int N = 16384;
constexpr int BKI = 1024;                 // k-ints per tile (4 KB per row)
constexpr int NT = K / BKI;               // 4 tiles
constexpr int PITCH = 4096 + 16;          // LDS bytes per row (16B-aligned pad)
constexpr size_t XB_OFF = 0;              // bf16 x: 32*4096*2 = 256 KB in d_ws

// fp32 -> bf16 RNE (finite inputs).
__device__ inline unsigned short f2bf_rne(float f) {
    unsigned u = __builtin_bit_cast(unsigned, f);
    u += 0x7FFF + ((u >> 16) & 1);
    return (unsigned short)(u >> 16);
}

// 8 int32 weights -> 8 bf16, exact (|w|<=127; fp32->bf16 truncation lossless).
__device__ inline bf16x8 cvtW(i32x4 lo, i32x4 hi) {
    s16x8 r;
#pragma unroll
    for (int i = 0; i < 4; ++i) {
        r[i]     = (short)(__builtin_bit_cast(unsigned, (float)lo[i]) >> 16);
        r[i + 4] = (short)(__builtin_bit_cast(unsigned, (float)hi[i]) >> 16);
    }
    return __builtin_bit_cast(bf16x8, r);
}

// ---- k1: x fp32 -> bf16 ----------------------------------------------------
__global__ __launch_bounds__(256) void xcvt_kernel(const float* __restrict__ x,
                                                   unsigned short* __restrict__ xb) {
    const int i = (blockIdx.x * 256 + threadIdx.x) * 8;
    f32x4 lo = *reinterpret_cast<const f32x4*>(x + i);
    f32x4 hi = *reinterpret_cast<const f32x4*>(x + i + 4);
    s16x8 r;
#pragma unroll
    for (int j = 0; j < 4; ++j) {
        r[j]     = (short)f2bf_rne(lo[j]);
        r[j + 4] = (short)f2bf_rne(hi[j]);
    }
    *reinterpret_cast<s16x8*>(xb + i) = r;
}

// ---- k2: GEMM, 4 KB-contiguous-per-row staged tiles, NT weight reads -------
__global__ __launch_bounds__(256, 2) void w8gemm_kernel(
    const __bf16* __restrict__ xb,
    const int* __restrict__ w,
    const float* __restrict__ scale,
    const float* __restrict__ bias,
    float* __restrict__ out)
{
    extern __shared__ char smem[];   // 16 * PITCH = 65792 B

    const int tid  = threadIdx.x;
    const int lane = tid & 63;
    const int wave = tid >> 6;
    const int n16  = lane & 15;
    const int quad = lane >> 4;

    const int c0 = blockIdx.x * 16;       // 16 channels per block

    // Staging: wave w owns rows w*4..w*4+3; per tile, per row, 4 back-to-back
    // 1 KB global_load_lds -> 4 KB sequential in flight per row.
    // aux=2: NT (non-temporal) cache policy on the weight stream.
    auto stage = [&](int it) {
#pragma unroll
        for (int j = 0; j < 4; ++j) {
            const int row = wave * 4 + j;
            const char* gsrc = (const char*)(w + (size_t)(c0 + row) * K + it * BKI)
                               + (size_t)lane * 16;
            char* ldst = smem + row * PITCH + lane * 16;
#pragma unroll
            for (int s = 0; s < 4; ++s) {
                __builtin_amdgcn_global_load_lds(
                    (const __attribute__((address_space(1))) void*)(gsrc + s * 1024),
                    (__attribute__((address_space(3))) void*)(ldst + s * 1024),
                    16, 0, 2 /* NT */);
            }
        }
    };

    // Compute: wave w consumes k-ints [w*256, w*256+256) of each tile.
    // B fragment (16x16x32): row n16, ints quad*8..+7 -> 2 x b128 from LDS.
    const char* lrow = smem + n16 * PITCH + quad * 32 + wave * 1024;
    // A fragments from bf16 x (L2-hot): token n16 (acc0), n16+16 (acc1).
    const __bf16* __restrict__ xr0 = xb + (size_t)n16 * K + wave * 256 + quad * 8;
    const __bf16* __restrict__ xr1 = xr0 + (size_t)16 * K;

    f32x4 acc0 = {0.f, 0.f, 0.f, 0.f};
    f32x4 acc1 = {0.f, 0.f, 0.f, 0.f};

    stage(0);
#pragma unroll 1
    for (int it = 0; it < NT; ++it) {
        // Prefetch this tile's x fragments (8 k-steps x 2 halves x 16 B).
        bf16x8 aX0[8], aX1[8];
#pragma unroll
        for (int j = 0; j < 8; ++j) {
            const int off = it * BKI + j * 32;
            aX0[j] = *reinterpret_cast<const bf16x8*>(xr0 + off);
            aX1[j] = *reinterpret_cast<const bf16x8*>(xr1 + off);
        }
        __syncthreads();   // staging complete
#pragma unroll
        for (int j = 0; j < 8; ++j) {
            i32x4 b0 = *reinterpret_cast<const i32x4*>(lrow + j * 128);
            i32x4 b1 = *reinterpret_cast<const i32x4*>(lrow + j * 128 + 16);
            bf16x8 bf = cvtW(b0, b1);
            acc0 = __builtin_amdgcn_mfma_f32_16x16x32_bf16(aX0[j], bf, acc0, 0, 0, 0);
            acc1 = __builtin_amdgcn_mfma_f32_16x16x32_bf16(aX1[j], bf, acc1, 0, 0, 0);
        }
        __syncthreads();   // reads done before restaging the single buffer
        if (it + 1 < NT) stage(it + 1);
    }

    // Cross-wave reduction (4 k-quarter partials) + fused scale/bias epilogue.
    __syncthreads();
    float* red = (float*)smem;           // 4 waves x 512 floats = 8 KB
#pragma unroll
    for (int v = 0; v < 4; ++v) {
        red[wave * 512 + lane * 8 + v]     = acc0[v];
        red[wave * 512 + lane * 8 + 4 + v] = acc1[v];
    }
    __syncthreads();
#pragma unroll
    for (int pp = 0; pp < 2; ++pp) {
        const int p = tid + pp * 256;            // 0..511
        float s = red[p] + red[512 + p] + red[1024 + p] + red[1536 + p];
        const int pl   = p >> 3;                 // source lane
        const int r    = p & 7;
        const int half = r >> 2;                 // 0: tokens 0-15, 1: 16-31
        const int v    = r & 3;
        const int pn   = pl & 15;
        const int pq   = pl >> 4;
        const int token = half * 16 + pq * 4 + v;
        const int c = c0 + pn;
        out[(size_t)token * N + c] = s * scale[c] + bias[c];
    }
}

extern "C" void kernel_launch(void* const* d_in, const int* in_sizes, int n_in,
                              void* d_out, int out_size, void* d_ws, size_t ws_size,
                              hipStream_t stream) {
    const float* x     = (const float*)d_in[0];
    const int*   w     = (const int*)d_in[1];
    const float* scale = (const float*)d_in[2];
    const float* bias  = (const float*)d_in[3];
    float* out = (float*)d_out;

    unsigned short* xb = (unsigned short*)((char*)d_ws + XB_OFF);

    xcvt_kernel<<<dim3(64), dim3(256), 0, stream>>>(x, xb);
    w8gemm_kernel<<<dim3(N / 16), dim3(256), 16 * PITCH, stream>>>(
        (const __bf16*)xb, w, scale, bias, out);
}